// Round 4
// baseline (951.122 us; speedup 1.0000x reference)
//
#include <hip/hip_runtime.h>

// MinimalRNNCell h_t = x_t W + h_{t-1} R.  B=32 T=1024 D=512 U=1024, out fp32.
// R4: C=4 chunking (P1 depth 3, KS over 256 chunks = 8 steps at M=8192),
// pure-bf16 P0 via convert_x pass (kills the fp32-A staging path's 140 us).
//   convert_x, convert_wt, convert_rrm, convert_rt
//   PL: 9 z-batched power layers (20 mats, G/R families)
//   P0: XWL = x_bf @ W            (M=32768 K=512, bf16 out)
//   P1: in-place local scans j=1..3 (3 launches, M=8192)
//   P2: KS over 256 chunk-ends, ops G4..G512 (8 launches, M=8192)
//   P3: out = L_j + S_{c-1} G_{j+1} (ONE z=4 launch, fp32 out)

typedef __attribute__((ext_vector_type(4))) float  floatx4;
typedef __attribute__((ext_vector_type(4))) float  float4v;
typedef __attribute__((ext_vector_type(8))) short  short8v;
typedef __attribute__((ext_vector_type(4))) short  short4v;

__device__ __forceinline__ short f2bf(float f) {  // RNE
  unsigned u = __float_as_uint(f);
  u += 0x7fffu + ((u >> 16) & 1u);
  return (short)(u >> 16);
}
__device__ __forceinline__ float bf2f(unsigned short u) {
  return __uint_as_float((unsigned)u << 16);
}
__device__ __forceinline__ void ld16(short* lds, const void* g) {  // async 16B global->LDS
  __builtin_amdgcn_global_load_lds((const __attribute__((address_space(1))) unsigned*)g,
                                   (__attribute__((address_space(3))) unsigned*)lds, 16, 0, 0);
}

// row m (plus z): offset = base + z*zs + (m/div)*s1 + (m%div)*s2 ; valid iff m/div >= qmin
struct Addr { long base, s1, s2; int div, qmin; };
struct Op { const void* p[8]; Addr a; long zs; };

// ---------------------------------------------------------------------------
// OUT[z][m,n] = (HASD ? D : 0) + A[m,:]*B ; N=1024, BN=128, BK=64.
// A bf16 (fp32 if AF32), B bf16 [n][K], D bf16, OUT fp32/bf16. M % BM == 0.
// ---------------------------------------------------------------------------
template<int BM, bool AF32, bool OF32, bool HASD>
__global__ __launch_bounds__(256) void gemm_k(Op A, Op B, Op D, Op O, int M, int K,
                                              const unsigned short* zbuf)
{
  constexpr int BK = 64;
  constexpr int MF = BM / 32;          // m-frags per wave (WM=2)
  constexpr int NF = 4;                // n-frags per wave (WN=2)
  constexpr int ABR = BM / 32;         // bf16-A staging rounds
  constexpr int AFR = BM / 16;         // fp32-A staging rounds

  __shared__ __align__(16) short As[BM * BK];
  __shared__ __align__(16) short Bs[128 * BK];

  const int tid  = threadIdx.x;
  const int lane = tid & 63;
  const int wave = tid >> 6;
  const int wr = wave >> 1, wc = wave & 1;
  const int lm  = lane & 15;
  const int kof = (lane >> 4) * 8;

  const int z   = blockIdx.z;
  const int bm0 = blockIdx.x * BM;     // M on x: one M-tile's N-group shares an XCD
  const int bn0 = blockIdx.y * 128;

  const long abase = A.a.base + (long)z * A.zs;

  const unsigned short* Bp = (const unsigned short*)B.p[z];
  const unsigned short* bgp[4];
#pragma unroll
  for (int r = 0; r < 4; ++r)
    bgp[r] = Bp + (long)(bn0 + r * 32 + tid / 8) * K + (tid % 8) * 8;

  const unsigned short* agp[AF32 ? 1 : ABR];
  const float* afp[AF32 ? AFR : 1];
  bool afv[AF32 ? AFR : 1];
  if constexpr (AF32) {
#pragma unroll
    for (int r = 0; r < AFR; ++r) {
      int m = bm0 + r * 16 + tid / 16;
      int q = m / A.a.div;
      afv[r] = (q >= A.a.qmin);
      long off = abase + (long)q * A.a.s1 + (long)(m % A.a.div) * A.a.s2 + (tid % 16) * 4;
      afp[r] = (const float*)A.p[z] + off;
    }
  } else {
#pragma unroll
    for (int r = 0; r < ABR; ++r) {
      int m = bm0 + r * 32 + tid / 8;
      int q = m / A.a.div;
      long off = abase + (long)q * A.a.s1 + (long)(m % A.a.div) * A.a.s2 + (tid % 8) * 8;
      agp[r] = (q >= A.a.qmin) ? (const unsigned short*)A.p[z] + off
                               : zbuf + (tid % 8) * 8;
    }
  }

  floatx4 acc[MF][NF] = {};

  for (int kb = 0; kb < K; kb += BK) {
    if constexpr (AF32) {
#pragma unroll
      for (int r = 0; r < AFR; ++r) {
        float4v v = afv[r] ? *(const float4v*)(afp[r] + kb) : (float4v)(0.f);
        short4v s; s.x = f2bf(v.x); s.y = f2bf(v.y); s.z = f2bf(v.z); s.w = f2bf(v.w);
        *(short4v*)&As[(r * 16 + tid / 16) * BK + (tid % 16) * 4] = s;
      }
    } else {
#pragma unroll
      for (int r = 0; r < ABR; ++r)
        ld16(&As[r * 2048 + tid * 8], agp[r] + kb);
    }
#pragma unroll
    for (int r = 0; r < 4; ++r)
      ld16(&Bs[r * 2048 + tid * 8], bgp[r] + kb);
    __syncthreads();
#pragma unroll
    for (int ks = 0; ks < 2; ++ks) {
      short8v af[MF], bfr[NF];
#pragma unroll
      for (int i = 0; i < MF; ++i)
        af[i] = *(const short8v*)&As[(wr * MF * 16 + i * 16 + lm) * BK + ks * 32 + kof];
#pragma unroll
      for (int j = 0; j < NF; ++j)
        bfr[j] = *(const short8v*)&Bs[(wc * 64 + j * 16 + lm) * BK + ks * 32 + kof];
#pragma unroll
      for (int i = 0; i < MF; ++i)
#pragma unroll
        for (int j = 0; j < NF; ++j)
          acc[i][j] = __builtin_amdgcn_mfma_f32_16x16x32_bf16(af[i], bfr[j], acc[i][j], 0, 0, 0);
    }
    __syncthreads();
  }

  const long obase = O.a.base + (long)z * O.zs;
  long dbase = 0; const unsigned short* Dp = nullptr;
  if constexpr (HASD) { dbase = D.a.base + (long)z * D.zs; Dp = (const unsigned short*)D.p[z]; }

#pragma unroll
  for (int i = 0; i < MF; ++i) {
#pragma unroll
    for (int r = 0; r < 4; ++r) {
      int m = bm0 + wr * MF * 16 + i * 16 + (lane >> 4) * 4 + r;  // C/D row=(lane>>4)*4+reg
      long ob = obase + (long)(m / O.a.div) * O.a.s1 + (long)(m % O.a.div) * O.a.s2;
      long db = 0;
      if constexpr (HASD) db = dbase + (long)(m / D.a.div) * D.a.s1 + (long)(m % D.a.div) * D.a.s2;
#pragma unroll
      for (int j = 0; j < NF; ++j) {
        int n = bn0 + wc * 64 + j * 16 + lm;
        float v = acc[i][j][r];
        if constexpr (HASD) v += bf2f(Dp[db + n]);
        if constexpr (OF32) ((float*)O.p[z])[ob + n] = v;
        else ((unsigned short*)O.p[z])[ob + n] = (unsigned short)f2bf(v);
      }
    }
  }
}

// --- converts ----------------------------------------------------------------
__global__ void convert_x(const float* x, unsigned short* xb) {  // 16.8M elems, 4/thread
  long i = ((long)blockIdx.x * 256 + threadIdx.x) * 4;
  float4v v = *(const float4v*)(x + i);
  short4v s; s.x = f2bf(v.x); s.y = f2bf(v.y); s.z = f2bf(v.z); s.w = f2bf(v.w);
  *(short4v*)(xb + i) = s;
}
__global__ void convert_wt(const float* W, unsigned short* Wt) {  // Wt[1024][512]
  int i = blockIdx.x * 256 + threadIdx.x;
  int n = i >> 9, k = i & 511;
  Wt[i] = (unsigned short)f2bf(W[(long)k * 1024 + n]);
}
__global__ void convert_rrm(const float* R, unsigned short* Rrm) {
  int i = blockIdx.x * 256 + threadIdx.x;
  Rrm[i] = (unsigned short)f2bf(R[i]);
}
__global__ void convert_rt(const float* R, unsigned short* Rt) {  // Rt[n][k]=R[k][n]
  int i = blockIdx.x * 256 + threadIdx.x;
  int n = i >> 10, k = i & 1023;
  Rt[i] = (unsigned short)f2bf(R[(long)k * 1024 + n]);
}

// --- host helpers ------------------------------------------------------------
static inline Op opS(const void* p, Addr a, long zs = 0) {
  Op o{}; for (int i = 0; i < 8; ++i) o.p[i] = p; o.a = a; o.zs = zs; return o;
}
static inline Addr contig(long base, long stride, int qmin = 0) {
  return Addr{base, stride, 0, 1, qmin};
}

template<int BM, bool AF32, bool OF32, bool HASD>
static inline void G(hipStream_t s, int M, int K, Op A, Op B, Op D, Op O,
                     const unsigned short* zbuf, int Z = 1) {
  dim3 grid(M / BM, 8, Z);
  hipLaunchKernelGGL((gemm_k<BM, AF32, OF32, HASD>), grid, dim3(256), 0, s,
                     A, B, D, O, M, K, zbuf);
}

extern "C" void kernel_launch(void* const* d_in, const int* in_sizes, int n_in,
                              void* d_out, int out_size, void* d_ws, size_t ws_size,
                              hipStream_t stream) {
  (void)in_sizes; (void)n_in; (void)out_size; (void)ws_size;
  const float* x = (const float*)d_in[0];     // [32,1024,512]
  const float* W = (const float*)d_in[2];     // [512,1024]
  const float* R = (const float*)d_in[3];     // [1024,1024]
  float* out = (float*)d_out;                 // [32,1024,1024]

  char* ws = (char*)d_ws;
  size_t off = 0;
  auto alloc = [&](size_t bytes) { void* p = ws + off; off += bytes; return p; };
  unsigned short* zbuf = (unsigned short*)alloc(4096);
  unsigned short* Wt = (unsigned short*)alloc(1024 * 512 * 2);
  auto mat = [&]() { return (unsigned short*)alloc(1024 * 1024 * 2); };
  unsigned short *Rt = mat(), *Rrm = mat();
  unsigned short *G2 = mat(), *R2 = mat(), *G3 = mat(), *G4 = mat(), *R4 = mat();
  unsigned short *G8 = mat(), *R8 = mat(), *G16 = mat(), *R16 = mat();
  unsigned short *G32 = mat(), *R32 = mat(), *G64 = mat(), *R64 = mat();
  unsigned short *G128 = mat(), *R128 = mat(), *G256 = mat(), *R256 = mat(), *G512 = mat();
  unsigned short* XWL = (unsigned short*)alloc((size_t)32 * 1024 * 1024 * 2);  // [b][t][u]
  unsigned short* x_bf = (unsigned short*)alloc((size_t)32 * 1024 * 512 * 2);  // dead after P0
  unsigned short* S0 = x_bf;                    // [c*32+b][u] bf16, 16 MiB (aliases x_bf)
  unsigned short* S1 = x_bf + (size_t)8192 * 1024;

  const Addr nil{0, 0, 0, 1, 0};
  const Addr c1024{0, 1024, 0, 1, 0};

  hipMemsetAsync(zbuf, 0, 4096, stream);
  hipLaunchKernelGGL(convert_x,   dim3(16384), dim3(256), 0, stream, x, x_bf);
  hipLaunchKernelGGL(convert_wt,  dim3(2048), dim3(256), 0, stream, W, Wt);
  hipLaunchKernelGGL(convert_rrm, dim3(4096), dim3(256), 0, stream, R, Rrm);
  hipLaunchKernelGGL(convert_rt,  dim3(4096), dim3(256), 0, stream, R, Rt);

  // P0: XWL = x_bf @ W (pure-bf16 path)
  G<128, false, false, false>(stream, 32768, 512,
      opS(x_bf, contig(0, 512)), opS(Wt, nil), opS(nullptr, nil), opS(XWL, c1024), zbuf);

  // power layers (z-batched): O_z = A_z * B_z, B arg = transposed operand
  auto PL = [&](int n, const unsigned short* const* Aa, const unsigned short* const* Bb,
                unsigned short* const* Oo) {
    Op A{}, B{}, D{}, O{};
    A.a = c1024; O.a = c1024; B.a = nil; D.a = nil;
    for (int i = 0; i < n; ++i) { A.p[i] = Aa[i]; B.p[i] = Bb[i]; O.p[i] = Oo[i]; }
    dim3 grid(1024 / 64, 8, n);
    hipLaunchKernelGGL((gemm_k<64, false, false, false>), grid, dim3(256), 0, stream,
                       A, B, D, O, 1024, 1024, zbuf);
  };
  { const unsigned short* Aa[] = {Rt, Rrm};            const unsigned short* Bb[] = {Rrm, Rt};
    unsigned short* Oo[] = {G2, R2};                   PL(2, Aa, Bb, Oo); }
  { const unsigned short* Aa[] = {G2, R2, G2};         const unsigned short* Bb[] = {R2, G2, Rrm};
    unsigned short* Oo[] = {G4, R4, G3};               PL(3, Aa, Bb, Oo); }
  { const unsigned short* Aa[] = {G4, R4};             const unsigned short* Bb[] = {R4, G4};
    unsigned short* Oo[] = {G8, R8};                   PL(2, Aa, Bb, Oo); }
  { const unsigned short* Aa[] = {G8, R8};             const unsigned short* Bb[] = {R8, G8};
    unsigned short* Oo[] = {G16, R16};                 PL(2, Aa, Bb, Oo); }
  { const unsigned short* Aa[] = {G16, R16};           const unsigned short* Bb[] = {R16, G16};
    unsigned short* Oo[] = {G32, R32};                 PL(2, Aa, Bb, Oo); }
  { const unsigned short* Aa[] = {G32, R32};           const unsigned short* Bb[] = {R32, G32};
    unsigned short* Oo[] = {G64, R64};                 PL(2, Aa, Bb, Oo); }
  { const unsigned short* Aa[] = {G64, R64};           const unsigned short* Bb[] = {R64, G64};
    unsigned short* Oo[] = {G128, R128};               PL(2, Aa, Bb, Oo); }
  { const unsigned short* Aa[] = {G128, R128};         const unsigned short* Bb[] = {R128, G128};
    unsigned short* Oo[] = {G256, R256};               PL(2, Aa, Bb, Oo); }
  { const unsigned short* Aa[] = {G256};               const unsigned short* Bb[] = {R256};
    unsigned short* Oo[] = {G512};                     PL(1, Aa, Bb, Oo); }

  // P1: in-place local scans, slots j=1..3 (rows m = c*32+b, c in [0,256))
  for (int j = 1; j <= 3; ++j) {
    Addr prev{(long)(j - 1) * 1024, 4096, 1048576, 32, 0};
    Addr cur {(long)j * 1024, 4096, 1048576, 32, 0};
    G<64, false, false, true>(stream, 8192, 1024,
        opS(XWL, prev), opS(Rt, nil), opS(XWL, cur), opS(XWL, cur), zbuf);
  }

  // P2: KS over 256 chunk carries. s=0: S0[c] = E_c + E_{c-1} @ G4 (E = slot 3)
  G<64, false, false, true>(stream, 8192, 1024,
      opS(XWL, Addr{3072 - 4096, 4096, 1048576, 32, 1}), opS(G4, nil),
      opS(XWL, Addr{3072, 4096, 1048576, 32, 0}), opS(S0, c1024), zbuf);
  { const unsigned short* ops[7] = {G8, G16, G32, G64, G128, G256, G512};
    unsigned short* buf[2] = {S0, S1};
    for (int s = 1; s <= 7; ++s) {
      unsigned short* Sp = buf[(s + 1) & 1];
      unsigned short* Sn = buf[s & 1];
      G<64, false, false, true>(stream, 8192, 1024,
          opS(Sp, contig(-((long)(32 << s) * 1024), 1024, 32 << s)), opS(ops[s - 1], nil),
          opS(Sp, c1024), opS(Sn, c1024), zbuf);
    }
  }
  // final inclusive carry in S1; carry into chunk c is S1[c-1]

  // P3: out[b][c*4+j] = L_j + S_{c-1} @ R^{j+1}  (z=j, one launch, fp32 out)
  {
    Op B{}; B.a = nil;
    const unsigned short* gj[4] = {Rt, G2, G3, G4};
    for (int i = 0; i < 4; ++i) B.p[i] = gj[i];
    Addr slot{0, 4096, 1048576, 32, 0};
    G<64, false, true, true>(stream, 8192, 1024,
        opS(S1, contig(-32768, 1024, 32)), B,
        opS(XWL, slot, 1024), opS(out, slot, 1024), zbuf, 4);
  }
}